// Round 5
// baseline (172.672 us; speedup 1.0000x reference)
//
#include <hip/hip_runtime.h>
#include <math.h>

#define BB 2
#define TT 512
#define UU 48
#define DD 512
#define HH 1024
#define KK 128

typedef __bf16 bf16x8 __attribute__((ext_vector_type(8)));
typedef float floatx4 __attribute__((ext_vector_type(4)));

// Padé(5,4) tanh, output-clamped: |err| < ~7e-4 everywhere.
__device__ __forceinline__ float tanh_fast(float x) {
    float x2 = x * x;
    float num = x * fmaf(x2, x2 + 105.0f, 945.0f);
    float den = fmaf(x2, fmaf(x2, 15.0f, 420.0f), 945.0f);
    float r = num * __fdividef(1.0f, den);
    return fminf(1.0f, fmaxf(-1.0f, r));
}

// ---------------- mid: imgH/labH/seg GEMMs + W2 swizzle, one dispatch -------
// region 0 (bid<256):   imgHb[r][n] = bf16(img·Wi)            M=1024 N=1024 K=512
// region 1 (256..279):  labHb[r][n] = bf16(lab·Wl + b1)       M=96   N=1024 K=512
// region 2 (280..311):  seg[b][k][t] = (img·cw + cb)*mask     M=1024 N=128  K=512
// region 3 (312..327):  W2s swizzle fp32->bf16
__global__ __launch_bounds__(256) void mid_kernel3(
    const float* __restrict__ img, const float* __restrict__ labf,
    const float* __restrict__ W1, const float* __restrict__ W2,
    const float* __restrict__ conv_w,
    const float* __restrict__ b1, const float* __restrict__ conv_b,
    const float* __restrict__ masks,
    __bf16* __restrict__ imgHb, __bf16* __restrict__ labHb,
    __bf16* __restrict__ W2s, float* __restrict__ seg_out) {
    int bid = blockIdx.x, tid = threadIdx.x;
    if (bid >= 312) {  // W2 swizzle: W2s[(h>>3)*1024 + k*8 + (h&7)] = W2[k][h]
        int base = (bid - 312) * 256 + tid;
#pragma unroll
        for (int i = 0; i < 32; ++i) {
            int o = base + i * 4096;
            int hg = o >> 10, kk2 = (o >> 3) & 127, hl = o & 7;
            W2s[o] = (__bf16)W2[(size_t)kk2 * HH + hg * 8 + hl];
        }
        return;
    }
    __shared__ __align__(16) __bf16 a_s[32][72];
    __shared__ __align__(16) __bf16 w_s[8192];
    const float* Arow;
    const float* Wbase;
    int r0, n0b, wstride, region;
    if (bid < 256) {
        region = 0; Arow = img; Wbase = W1 + 512; wstride = 1024;
        r0 = (bid & 31) * 32; n0b = (bid >> 5) * 128;
    } else if (bid < 280) {
        region = 1; Arow = labf; Wbase = W1; wstride = 1024;
        int i = bid - 256; r0 = (i % 3) * 32; n0b = (i / 3) * 128;
    } else {
        region = 2; Arow = img; Wbase = conv_w; wstride = 512;
        r0 = (bid - 280) * 32; n0b = 0;
    }
    int lane = tid & 63, wv = tid >> 6;
    int m0 = (wv & 1) * 16, n0w = (wv >> 1) * 64;
    int q = lane >> 4, r = lane & 15;
    int arow = tid >> 3, acol = (tid & 7) * 8;
    int wn = tid >> 3, wk = tid & 7;  // W stage: 8 consecutive threads = one n
    const float* aptr = &Arow[(size_t)(r0 + arow) * DD + acol];
    floatx4 acc[4] = {};
    float4 pa0, pa1, pw[4][2];
    // prefetch chunk 0
    pa0 = *(const float4*)aptr;
    pa1 = *(const float4*)(aptr + 4);
#pragma unroll
    for (int i2 = 0; i2 < 4; ++i2) {
        const float* wp_ = &Wbase[(size_t)(n0b + i2 * 32 + wn) * wstride + wk * 8];
        pw[i2][0] = *(const float4*)wp_;
        pw[i2][1] = *(const float4*)(wp_ + 4);
    }
    for (int c = 0; c < 8; ++c) {
        {   // staged regs -> LDS (bf16)
            bf16x8 av;
            av[0] = (__bf16)pa0.x; av[1] = (__bf16)pa0.y;
            av[2] = (__bf16)pa0.z; av[3] = (__bf16)pa0.w;
            av[4] = (__bf16)pa1.x; av[5] = (__bf16)pa1.y;
            av[6] = (__bf16)pa1.z; av[7] = (__bf16)pa1.w;
            *(bf16x8*)&a_s[arow][acol] = av;
#pragma unroll
            for (int i2 = 0; i2 < 4; ++i2) {
                bf16x8 wvv;
                wvv[0] = (__bf16)pw[i2][0].x; wvv[1] = (__bf16)pw[i2][0].y;
                wvv[2] = (__bf16)pw[i2][0].z; wvv[3] = (__bf16)pw[i2][0].w;
                wvv[4] = (__bf16)pw[i2][1].x; wvv[5] = (__bf16)pw[i2][1].y;
                wvv[6] = (__bf16)pw[i2][1].z; wvv[7] = (__bf16)pw[i2][1].w;
                *(bf16x8*)&w_s[((size_t)wk * 128 + i2 * 32 + wn) * 8] = wvv;
            }
        }
        __syncthreads();
        if (c < 7) {  // prefetch next chunk; overlaps MFMA below
            int cb = (c + 1) * 64;
            pa0 = *(const float4*)(aptr + cb);
            pa1 = *(const float4*)(aptr + cb + 4);
#pragma unroll
            for (int i2 = 0; i2 < 4; ++i2) {
                const float* wp_ =
                    &Wbase[(size_t)(n0b + i2 * 32 + wn) * wstride + cb + wk * 8];
                pw[i2][0] = *(const float4*)wp_;
                pw[i2][1] = *(const float4*)(wp_ + 4);
            }
        }
#pragma unroll
        for (int kt = 0; kt < 2; ++kt) {
            bf16x8 af = *(const bf16x8*)&a_s[m0 + r][kt * 32 + q * 8];
#pragma unroll
            for (int nt = 0; nt < 4; ++nt) {
                bf16x8 bfv = *(const bf16x8*)
                    &w_s[((kt * 4 + q) * 128 + n0w + nt * 16 + r) * 8];
                acc[nt] = __builtin_amdgcn_mfma_f32_16x16x32_bf16(
                    af, bfv, acc[nt], 0, 0, 0);
            }
        }
        __syncthreads();
    }
    if (region == 0) {
#pragma unroll
        for (int nt = 0; nt < 4; ++nt) {
            int n = n0b + n0w + nt * 16 + r;
#pragma unroll
            for (int rr = 0; rr < 4; ++rr)
                imgHb[(size_t)(r0 + m0 + 4 * q + rr) * HH + n] =
                    (__bf16)acc[nt][rr];
        }
    } else if (region == 1) {
#pragma unroll
        for (int nt = 0; nt < 4; ++nt) {
            int n = n0b + n0w + nt * 16 + r;
            float bv = b1[n];
#pragma unroll
            for (int rr = 0; rr < 4; ++rr)
                labHb[(size_t)(r0 + m0 + 4 * q + rr) * HH + n] =
                    (__bf16)(acc[nt][rr] + bv);
        }
    } else {
#pragma unroll
        for (int nt = 0; nt < 4; ++nt) {
            int k = n0w + nt * 16 + r;
            float bv = conv_b[k];
#pragma unroll
            for (int rr = 0; rr < 4; ++rr) {
                int row = r0 + m0 + 4 * q + rr;
                int b = row >> 9, t = row & 511;
                seg_out[((size_t)b * KK + k) * TT + t] =
                    (acc[nt][rr] + bv) * masks[row];
            }
        }
    }
}

// ---------------- joint: barrier-free, zero-LDS, tanh straight into A-frags --
// Each lane owns row (t0 + wv*16 + r), cols q*8 / 32+q*8 per chunk: exactly its
// MFMA A-fragment. B-frags read directly from L1/L2-resident swizzled W2s.
__global__ __launch_bounds__(256) void joint_kernel4(
    const __bf16* __restrict__ imgHb,  // [B*T][H]
    const __bf16* __restrict__ labHb,  // [B*U][H] (b1 folded)
    const __bf16* __restrict__ W2s,    // swizzled [(h>>3)][k][h&7]
    const float* __restrict__ b2,
    float* __restrict__ out) {         // [B*U*T][K]
    int tid = threadIdx.x, bid = blockIdx.x;
    int t0 = (bid & 7) * 64;
    int rest = bid >> 3;
    int u = rest % UU, b = rest / UU;
    int lane = tid & 63, wv = tid >> 6;
    int q = lane >> 4, r = lane & 15;
    const __bf16* imgrow = imgHb + ((size_t)b * TT + t0 + wv * 16 + r) * HH;
    const __bf16* labrow = labHb + (size_t)(b * UU + u) * HH;
    const __bf16* wbase = W2s + q * 1024 + r * 8;
    int c0 = q * 8, c1 = 32 + q * 8;
    floatx4 acc[8] = {};
    // prologue: chunk-0 inputs
    bf16x8 ivA = *(const bf16x8*)&imgrow[c0];
    bf16x8 ivB = *(const bf16x8*)&imgrow[c1];
    bf16x8 lvA = *(const bf16x8*)&labrow[c0];
    bf16x8 lvB = *(const bf16x8*)&labrow[c1];
    for (int c = 0; c < 16; ++c) {
        bf16x8 a0, a1;
#pragma unroll
        for (int i = 0; i < 8; ++i) {
            a0[i] = (__bf16)tanh_fast((float)ivA[i] + (float)lvA[i]);
            a1[i] = (__bf16)tanh_fast((float)ivB[i] + (float)lvB[i]);
        }
        if (c < 15) {  // prefetch next chunk; hides under MFMA chain
            int cb = (c + 1) * 64;
            ivA = *(const bf16x8*)&imgrow[cb + c0];
            ivB = *(const bf16x8*)&imgrow[cb + c1];
            lvA = *(const bf16x8*)&labrow[cb + c0];
            lvB = *(const bf16x8*)&labrow[cb + c1];
        }
        const __bf16* wc = wbase + (size_t)c * 8192;
#pragma unroll
        for (int nt = 0; nt < 8; ++nt) {
            bf16x8 bf0 = *(const bf16x8*)&wc[nt * 128];
            acc[nt] = __builtin_amdgcn_mfma_f32_16x16x32_bf16(
                a0, bf0, acc[nt], 0, 0, 0);
        }
#pragma unroll
        for (int nt = 0; nt < 8; ++nt) {
            bf16x8 bf1 = *(const bf16x8*)&wc[4096 + nt * 128];
            acc[nt] = __builtin_amdgcn_mfma_f32_16x16x32_bf16(
                a1, bf1, acc[nt], 0, 0, 0);
        }
    }
    // epilogue: +b2, in-register log-softmax over this 16-lane group's 128 cols
    float b2v[8];
#pragma unroll
    for (int nt = 0; nt < 8; ++nt) b2v[nt] = b2[nt * 16 + r];
    float* orow = out + (((size_t)b * UU + u) * TT + t0 + wv * 16) * KK;
#pragma unroll
    for (int rr = 0; rr < 4; ++rr) {
        float v[8];
        float mx = -INFINITY;
#pragma unroll
        for (int nt = 0; nt < 8; ++nt) {
            v[nt] = acc[nt][rr] + b2v[nt];
            mx = fmaxf(mx, v[nt]);
        }
        mx = fmaxf(mx, __shfl_xor(mx, 1, 16));
        mx = fmaxf(mx, __shfl_xor(mx, 2, 16));
        mx = fmaxf(mx, __shfl_xor(mx, 4, 16));
        mx = fmaxf(mx, __shfl_xor(mx, 8, 16));
        float s = 0.f;
#pragma unroll
        for (int nt = 0; nt < 8; ++nt) s += __expf(v[nt] - mx);
        s += __shfl_xor(s, 1, 16);
        s += __shfl_xor(s, 2, 16);
        s += __shfl_xor(s, 4, 16);
        s += __shfl_xor(s, 8, 16);
        float lse = mx + __logf(s);
        int row = 4 * q + rr;
#pragma unroll
        for (int nt = 0; nt < 8; ++nt)
            orow[(size_t)row * KK + nt * 16 + r] = v[nt] - lse;
    }
}

extern "C" void kernel_launch(void* const* d_in, const int* in_sizes, int n_in,
                              void* d_out, int out_size, void* d_ws, size_t ws_size,
                              hipStream_t stream) {
    const float* img    = (const float*)d_in[0];
    const float* labf   = (const float*)d_in[1];
    const float* masks  = (const float*)d_in[2];
    const float* W1     = (const float*)d_in[3];
    const float* b1     = (const float*)d_in[4];
    const float* W2     = (const float*)d_in[5];
    const float* b2     = (const float*)d_in[6];
    const float* conv_w = (const float*)d_in[7];
    const float* conv_b = (const float*)d_in[8];
    float* out = (float*)d_out;

    __bf16* base   = (__bf16*)d_ws;
    __bf16* imgHb  = base;                    // [1024][1024]
    __bf16* labHb  = imgHb + 1024 * 1024;     // [96][1024]
    __bf16* W2s    = labHb + 96 * 1024;       // [H/8][K][8] = 131072

    mid_kernel3<<<328, 256, 0, stream>>>(img, labf, W1, W2, conv_w,
                                         b1, conv_b, masks,
                                         imgHb, labHb, W2s, out);
    joint_kernel4<<<768, 256, 0, stream>>>(imgHb, labHb, W2s, b2,
                                           out + (size_t)BB * KK * TT);
}

// Round 6
// 128.539 us; speedup vs baseline: 1.3433x; 1.3433x over previous
//
#include <hip/hip_runtime.h>
#include <math.h>

#define BB 2
#define TT 512
#define UU 48
#define DD 512
#define HH 1024
#define KK 128

typedef _Float16 f16x8 __attribute__((ext_vector_type(8)));
typedef float floatx4 __attribute__((ext_vector_type(4)));

// Padé(5,4) tanh, output-clamped: |err| < ~7e-4 everywhere.
__device__ __forceinline__ float tanh_fast(float x) {
    float x2 = x * x;
    float num = x * fmaf(x2, x2 + 105.0f, 945.0f);
    float den = fmaf(x2, fmaf(x2, 15.0f, 420.0f), 945.0f);
    float r = num * __builtin_amdgcn_rcpf(den);
    return fminf(1.0f, fmaxf(-1.0f, r));
}

// ---------------- mid: imgH/labH/seg GEMMs + W2 swizzle, one dispatch -------
// region 0 (bid<256):   imgHf[r][n] = f16(img·Wi)             M=1024 N=1024 K=512
// region 1 (256..279):  labHf[r][n] = f16(lab·Wl + b1)        M=96   N=1024 K=512
// region 2 (280..311):  seg[b][k][t] = (img·cw + cb)*mask     M=1024 N=128  K=512
// region 3 (312..327):  W2s swizzle fp32->f16
__global__ __launch_bounds__(256) void mid_kernel4(
    const float* __restrict__ img, const float* __restrict__ labf,
    const float* __restrict__ W1, const float* __restrict__ W2,
    const float* __restrict__ conv_w,
    const float* __restrict__ b1, const float* __restrict__ conv_b,
    const float* __restrict__ masks,
    _Float16* __restrict__ imgHf, _Float16* __restrict__ labHf,
    _Float16* __restrict__ W2s, float* __restrict__ seg_out) {
    int bid = blockIdx.x, tid = threadIdx.x;
    if (bid >= 312) {  // W2 swizzle: W2s[(h>>3)*1024 + k*8 + (h&7)] = W2[k][h]
        int base = (bid - 312) * 256 + tid;
#pragma unroll
        for (int i = 0; i < 32; ++i) {
            int o = base + i * 4096;
            int hg = o >> 10, kk2 = (o >> 3) & 127, hl = o & 7;
            W2s[o] = (_Float16)W2[(size_t)kk2 * HH + hg * 8 + hl];
        }
        return;
    }
    __shared__ __align__(16) _Float16 a_s[32][72];
    __shared__ __align__(16) _Float16 w_s[8192];
    const float* Arow;
    const float* Wbase;
    int r0, n0b, wstride, region;
    if (bid < 256) {
        region = 0; Arow = img; Wbase = W1 + 512; wstride = 1024;
        r0 = (bid & 31) * 32; n0b = (bid >> 5) * 128;
    } else if (bid < 280) {
        region = 1; Arow = labf; Wbase = W1; wstride = 1024;
        int i = bid - 256; r0 = (i % 3) * 32; n0b = (i / 3) * 128;
    } else {
        region = 2; Arow = img; Wbase = conv_w; wstride = 512;
        r0 = (bid - 280) * 32; n0b = 0;
    }
    int lane = tid & 63, wv = tid >> 6;
    int m0 = (wv & 1) * 16, n0w = (wv >> 1) * 64;
    int q = lane >> 4, r = lane & 15;
    int arow = tid >> 3, acol = (tid & 7) * 8;
    int wn = tid >> 3, wk = tid & 7;  // W stage: 8 consecutive threads = one n
    const float* aptr = &Arow[(size_t)(r0 + arow) * DD + acol];
    floatx4 acc[4] = {};
    float4 pa0, pa1, pw[4][2];
    pa0 = *(const float4*)aptr;
    pa1 = *(const float4*)(aptr + 4);
#pragma unroll
    for (int i2 = 0; i2 < 4; ++i2) {
        const float* wp_ = &Wbase[(size_t)(n0b + i2 * 32 + wn) * wstride + wk * 8];
        pw[i2][0] = *(const float4*)wp_;
        pw[i2][1] = *(const float4*)(wp_ + 4);
    }
    for (int c = 0; c < 8; ++c) {
        {
            f16x8 av;
            av[0] = (_Float16)pa0.x; av[1] = (_Float16)pa0.y;
            av[2] = (_Float16)pa0.z; av[3] = (_Float16)pa0.w;
            av[4] = (_Float16)pa1.x; av[5] = (_Float16)pa1.y;
            av[6] = (_Float16)pa1.z; av[7] = (_Float16)pa1.w;
            *(f16x8*)&a_s[arow][acol] = av;
#pragma unroll
            for (int i2 = 0; i2 < 4; ++i2) {
                f16x8 wvv;
                wvv[0] = (_Float16)pw[i2][0].x; wvv[1] = (_Float16)pw[i2][0].y;
                wvv[2] = (_Float16)pw[i2][0].z; wvv[3] = (_Float16)pw[i2][0].w;
                wvv[4] = (_Float16)pw[i2][1].x; wvv[5] = (_Float16)pw[i2][1].y;
                wvv[6] = (_Float16)pw[i2][1].z; wvv[7] = (_Float16)pw[i2][1].w;
                *(f16x8*)&w_s[((size_t)wk * 128 + i2 * 32 + wn) * 8] = wvv;
            }
        }
        __syncthreads();
        if (c < 7) {
            int cb = (c + 1) * 64;
            pa0 = *(const float4*)(aptr + cb);
            pa1 = *(const float4*)(aptr + cb + 4);
#pragma unroll
            for (int i2 = 0; i2 < 4; ++i2) {
                const float* wp_ =
                    &Wbase[(size_t)(n0b + i2 * 32 + wn) * wstride + cb + wk * 8];
                pw[i2][0] = *(const float4*)wp_;
                pw[i2][1] = *(const float4*)(wp_ + 4);
            }
        }
#pragma unroll
        for (int kt = 0; kt < 2; ++kt) {
            f16x8 af = *(const f16x8*)&a_s[m0 + r][kt * 32 + q * 8];
#pragma unroll
            for (int nt = 0; nt < 4; ++nt) {
                f16x8 bfv = *(const f16x8*)
                    &w_s[((kt * 4 + q) * 128 + n0w + nt * 16 + r) * 8];
                acc[nt] = __builtin_amdgcn_mfma_f32_16x16x32_f16(
                    af, bfv, acc[nt], 0, 0, 0);
            }
        }
        __syncthreads();
    }
    if (region == 0) {
#pragma unroll
        for (int nt = 0; nt < 4; ++nt) {
            int n = n0b + n0w + nt * 16 + r;
#pragma unroll
            for (int rr = 0; rr < 4; ++rr)
                imgHf[(size_t)(r0 + m0 + 4 * q + rr) * HH + n] =
                    (_Float16)acc[nt][rr];
        }
    } else if (region == 1) {
#pragma unroll
        for (int nt = 0; nt < 4; ++nt) {
            int n = n0b + n0w + nt * 16 + r;
            float bv = b1[n];
#pragma unroll
            for (int rr = 0; rr < 4; ++rr)
                labHf[(size_t)(r0 + m0 + 4 * q + rr) * HH + n] =
                    (_Float16)(acc[nt][rr] + bv);
        }
    } else {
#pragma unroll
        for (int nt = 0; nt < 4; ++nt) {
            int k = n0w + nt * 16 + r;
            float bv = conv_b[k];
#pragma unroll
            for (int rr = 0; rr < 4; ++rr) {
                int row = r0 + m0 + 4 * q + rr;
                int b = row >> 9, t = row & 511;
                seg_out[((size_t)b * KK + k) * TT + t] =
                    (acc[nt][rr] + bv) * masks[row];
            }
        }
    }
}

// ---------------- joint: zero-LDS h (tanh -> A-frags in regs), dbuf LDS W2,
// one barrier/chunk, fp16 everywhere, in-register log-softmax.
__global__ __launch_bounds__(256) void joint_kernel5(
    const _Float16* __restrict__ imgHf,  // [B*T][H]
    const _Float16* __restrict__ labHf,  // [B*U][H] (b1 folded)
    const _Float16* __restrict__ W2s,    // swizzled [(h>>3)][k][h&7]
    const float* __restrict__ b2,
    float* __restrict__ out) {           // [B*U*T][K]
    __shared__ __align__(16) _Float16 w_s[2][8192];  // 2 x 16 KB
    int tid = threadIdx.x, bid = blockIdx.x;
    int t0 = (bid & 7) * 64;
    int rest = bid >> 3;
    int u = rest % UU, b = rest / UU;
    int lane = tid & 63, wv = tid >> 6;
    int q = lane >> 4, r = lane & 15;
    // this lane's h row and A-fragment columns
    const _Float16* imgrow = imgHf + ((size_t)b * TT + t0 + wv * 16 + r) * HH;
    const _Float16* labrow = labHf + (size_t)(b * UU + u) * HH;
    int c0 = q * 8, c1 = 32 + q * 8;
    // W2 cooperative staging: thread stages 4 x 16B per chunk
    int ws_off = tid * 8;  // elements; thread covers [tid*8 + i*2048*... ] pattern below
    floatx4 acc[8] = {};
    // prologue: chunk 0 W2 -> LDS buf0; img/lab chunk 0 -> regs
    f16x8 ivA = *(const f16x8*)&imgrow[c0];
    f16x8 ivB = *(const f16x8*)&imgrow[c1];
    f16x8 lvA = *(const f16x8*)&labrow[c0];
    f16x8 lvB = *(const f16x8*)&labrow[c1];
    {
        const _Float16* wsrc = W2s;
#pragma unroll
        for (int i2 = 0; i2 < 4; ++i2)
            *(f16x8*)&w_s[0][i2 * 2048 + ws_off] =
                *(const f16x8*)&wsrc[i2 * 2048 + ws_off];
    }
    __syncthreads();
#pragma unroll 2
    for (int c = 0; c < 16; ++c) {
        int buf = c & 1;
        // issue next chunk's loads first; they drain during tanh+MFMA
        f16x8 nivA, nivB, nlvA, nlvB, nw0, nw1, nw2, nw3;
        if (c < 15) {
            int cb = (c + 1) * 64;
            nivA = *(const f16x8*)&imgrow[cb + c0];
            nivB = *(const f16x8*)&imgrow[cb + c1];
            nlvA = *(const f16x8*)&labrow[cb + c0];
            nlvB = *(const f16x8*)&labrow[cb + c1];
            const _Float16* wsrc = W2s + (size_t)(c + 1) * 8192;
            nw0 = *(const f16x8*)&wsrc[0 * 2048 + ws_off];
            nw1 = *(const f16x8*)&wsrc[1 * 2048 + ws_off];
            nw2 = *(const f16x8*)&wsrc[2 * 2048 + ws_off];
            nw3 = *(const f16x8*)&wsrc[3 * 2048 + ws_off];
        }
        // h = tanh(img + lab): packed f16 add, f32 tanh, straight into A-frags
        f16x8 s0 = ivA + lvA;   // v_pk_add_f16
        f16x8 s1 = ivB + lvB;
        f16x8 a0, a1;
#pragma unroll
        for (int i = 0; i < 8; ++i) {
            a0[i] = (_Float16)tanh_fast((float)s0[i]);
            a1[i] = (_Float16)tanh_fast((float)s1[i]);
        }
#pragma unroll
        for (int nt = 0; nt < 8; ++nt) {
            f16x8 bf0 = *(const f16x8*)&w_s[buf][((0 + q) * 128 + nt * 16 + r) * 8];
            acc[nt] = __builtin_amdgcn_mfma_f32_16x16x32_f16(
                a0, bf0, acc[nt], 0, 0, 0);
        }
#pragma unroll
        for (int nt = 0; nt < 8; ++nt) {
            f16x8 bf1 = *(const f16x8*)&w_s[buf][((4 + q) * 128 + nt * 16 + r) * 8];
            acc[nt] = __builtin_amdgcn_mfma_f32_16x16x32_f16(
                a1, bf1, acc[nt], 0, 0, 0);
        }
        if (c < 15) {  // stage next W2 chunk into other buffer; rotate regs
            *(f16x8*)&w_s[buf ^ 1][0 * 2048 + ws_off] = nw0;
            *(f16x8*)&w_s[buf ^ 1][1 * 2048 + ws_off] = nw1;
            *(f16x8*)&w_s[buf ^ 1][2 * 2048 + ws_off] = nw2;
            *(f16x8*)&w_s[buf ^ 1][3 * 2048 + ws_off] = nw3;
            ivA = nivA; ivB = nivB; lvA = nlvA; lvB = nlvB;
        }
        __syncthreads();
    }
    // epilogue: +b2, in-register log-softmax over this 16-lane group's 128 cols
    float b2v[8];
#pragma unroll
    for (int nt = 0; nt < 8; ++nt) b2v[nt] = b2[nt * 16 + r];
    float* orow = out + (((size_t)b * UU + u) * TT + t0 + wv * 16) * KK;
#pragma unroll
    for (int rr = 0; rr < 4; ++rr) {
        float v[8];
        float mx = -INFINITY;
#pragma unroll
        for (int nt = 0; nt < 8; ++nt) {
            v[nt] = acc[nt][rr] + b2v[nt];
            mx = fmaxf(mx, v[nt]);
        }
        mx = fmaxf(mx, __shfl_xor(mx, 1, 16));
        mx = fmaxf(mx, __shfl_xor(mx, 2, 16));
        mx = fmaxf(mx, __shfl_xor(mx, 4, 16));
        mx = fmaxf(mx, __shfl_xor(mx, 8, 16));
        float s = 0.f;
#pragma unroll
        for (int nt = 0; nt < 8; ++nt) s += __expf(v[nt] - mx);
        s += __shfl_xor(s, 1, 16);
        s += __shfl_xor(s, 2, 16);
        s += __shfl_xor(s, 4, 16);
        s += __shfl_xor(s, 8, 16);
        float lse = mx + __logf(s);
        int row = 4 * q + rr;
#pragma unroll
        for (int nt = 0; nt < 8; ++nt)
            orow[(size_t)row * KK + nt * 16 + r] = v[nt] - lse;
    }
}

extern "C" void kernel_launch(void* const* d_in, const int* in_sizes, int n_in,
                              void* d_out, int out_size, void* d_ws, size_t ws_size,
                              hipStream_t stream) {
    const float* img    = (const float*)d_in[0];
    const float* labf   = (const float*)d_in[1];
    const float* masks  = (const float*)d_in[2];
    const float* W1     = (const float*)d_in[3];
    const float* b1     = (const float*)d_in[4];
    const float* W2     = (const float*)d_in[5];
    const float* b2     = (const float*)d_in[6];
    const float* conv_w = (const float*)d_in[7];
    const float* conv_b = (const float*)d_in[8];
    float* out = (float*)d_out;

    _Float16* base  = (_Float16*)d_ws;
    _Float16* imgHf = base;                    // [1024][1024]
    _Float16* labHf = imgHf + 1024 * 1024;     // [96][1024]
    _Float16* W2s   = labHf + 96 * 1024;       // [H/8][K][8] = 131072

    mid_kernel4<<<328, 256, 0, stream>>>(img, labf, W1, W2, conv_w,
                                         b1, conv_b, masks,
                                         imgHf, labHf, W2s, out);
    joint_kernel5<<<768, 256, 0, stream>>>(imgHf, labHf, W2s, b2,
                                           out + (size_t)BB * KK * TT);
}

// Round 8
// 123.627 us; speedup vs baseline: 1.3967x; 1.0397x over previous
//
#include <hip/hip_runtime.h>
#include <math.h>

#define BB 2
#define TT 512
#define UU 48
#define DD 512
#define HH 1024
#define KK 128

typedef _Float16 f16x8 __attribute__((ext_vector_type(8)));
typedef __fp16 fp16x2_t __attribute__((ext_vector_type(2)));
typedef float floatx4 __attribute__((ext_vector_type(4)));

// tanh(x) = 1 - 2/(e^{2x}+1). ~7 VALU inst/elem, safe at +-inf (no clamp).
// Packs pairs with v_cvt_pkrtz_f16_f32.
__device__ __forceinline__ f16x8 tanh8(f16x8 x) {
    f16x8 o;
#pragma unroll
    for (int i = 0; i < 8; i += 2) {
        float s0 = (float)x[i];
        float s1 = (float)x[i + 1];
        float e0 = __expf(s0 + s0);
        float e1 = __expf(s1 + s1);
        float r0 = __builtin_amdgcn_rcpf(e0 + 1.0f);
        float r1 = __builtin_amdgcn_rcpf(e1 + 1.0f);
        fp16x2_t p = __builtin_amdgcn_cvt_pkrtz(fmaf(-2.0f, r0, 1.0f),
                                                fmaf(-2.0f, r1, 1.0f));
        o[i] = (_Float16)p[0];
        o[i + 1] = (_Float16)p[1];
    }
    return o;
}

// ---------------- mid: imgH/labH/seg GEMMs + W2 swizzle, one dispatch -------
// region 0 (bid<256):   imgHf[r][n] = f16(img·Wi)             M=1024 N=1024 K=512
// region 1 (256..279):  labHf[r][n] = f16(lab·Wl + b1)        M=96   N=1024 K=512
// region 2 (280..311):  seg[b][k][t] = (img·cw + cb)*mask     M=1024 N=128  K=512
// region 3 (312..327):  W2s swizzle fp32->f16
__global__ __launch_bounds__(256) void mid_kernel4(
    const float* __restrict__ img, const float* __restrict__ labf,
    const float* __restrict__ W1, const float* __restrict__ W2,
    const float* __restrict__ conv_w,
    const float* __restrict__ b1, const float* __restrict__ conv_b,
    const float* __restrict__ masks,
    _Float16* __restrict__ imgHf, _Float16* __restrict__ labHf,
    _Float16* __restrict__ W2s, float* __restrict__ seg_out) {
    int bid = blockIdx.x, tid = threadIdx.x;
    if (bid >= 312) {  // W2 swizzle: W2s[(h>>3)*1024 + k*8 + (h&7)] = W2[k][h]
        int base = (bid - 312) * 256 + tid;
#pragma unroll
        for (int i = 0; i < 32; ++i) {
            int o = base + i * 4096;
            int hg = o >> 10, kk2 = (o >> 3) & 127, hl = o & 7;
            W2s[o] = (_Float16)W2[(size_t)kk2 * HH + hg * 8 + hl];
        }
        return;
    }
    __shared__ __align__(16) _Float16 a_s[32][72];
    __shared__ __align__(16) _Float16 w_s[8192];
    const float* Arow;
    const float* Wbase;
    int r0, n0b, wstride, region;
    if (bid < 256) {
        region = 0; Arow = img; Wbase = W1 + 512; wstride = 1024;
        r0 = (bid & 31) * 32; n0b = (bid >> 5) * 128;
    } else if (bid < 280) {
        region = 1; Arow = labf; Wbase = W1; wstride = 1024;
        int i = bid - 256; r0 = (i % 3) * 32; n0b = (i / 3) * 128;
    } else {
        region = 2; Arow = img; Wbase = conv_w; wstride = 512;
        r0 = (bid - 280) * 32; n0b = 0;
    }
    int lane = tid & 63, wv = tid >> 6;
    int m0 = (wv & 1) * 16, n0w = (wv >> 1) * 64;
    int q = lane >> 4, r = lane & 15;
    int arow = tid >> 3, acol = (tid & 7) * 8;
    int wn = tid >> 3, wk = tid & 7;  // W stage: 8 consecutive threads = one n
    const float* aptr = &Arow[(size_t)(r0 + arow) * DD + acol];
    floatx4 acc[4] = {};
    float4 pa0, pa1, pw[4][2];
    pa0 = *(const float4*)aptr;
    pa1 = *(const float4*)(aptr + 4);
#pragma unroll
    for (int i2 = 0; i2 < 4; ++i2) {
        const float* wp_ = &Wbase[(size_t)(n0b + i2 * 32 + wn) * wstride + wk * 8];
        pw[i2][0] = *(const float4*)wp_;
        pw[i2][1] = *(const float4*)(wp_ + 4);
    }
    for (int c = 0; c < 8; ++c) {
        {
            f16x8 av;
            av[0] = (_Float16)pa0.x; av[1] = (_Float16)pa0.y;
            av[2] = (_Float16)pa0.z; av[3] = (_Float16)pa0.w;
            av[4] = (_Float16)pa1.x; av[5] = (_Float16)pa1.y;
            av[6] = (_Float16)pa1.z; av[7] = (_Float16)pa1.w;
            *(f16x8*)&a_s[arow][acol] = av;
#pragma unroll
            for (int i2 = 0; i2 < 4; ++i2) {
                f16x8 wvv;
                wvv[0] = (_Float16)pw[i2][0].x; wvv[1] = (_Float16)pw[i2][0].y;
                wvv[2] = (_Float16)pw[i2][0].z; wvv[3] = (_Float16)pw[i2][0].w;
                wvv[4] = (_Float16)pw[i2][1].x; wvv[5] = (_Float16)pw[i2][1].y;
                wvv[6] = (_Float16)pw[i2][1].z; wvv[7] = (_Float16)pw[i2][1].w;
                *(f16x8*)&w_s[((size_t)wk * 128 + i2 * 32 + wn) * 8] = wvv;
            }
        }
        __syncthreads();
        if (c < 7) {
            int cb = (c + 1) * 64;
            pa0 = *(const float4*)(aptr + cb);
            pa1 = *(const float4*)(aptr + cb + 4);
#pragma unroll
            for (int i2 = 0; i2 < 4; ++i2) {
                const float* wp_ =
                    &Wbase[(size_t)(n0b + i2 * 32 + wn) * wstride + cb + wk * 8];
                pw[i2][0] = *(const float4*)wp_;
                pw[i2][1] = *(const float4*)(wp_ + 4);
            }
        }
#pragma unroll
        for (int kt = 0; kt < 2; ++kt) {
            f16x8 af = *(const f16x8*)&a_s[m0 + r][kt * 32 + q * 8];
#pragma unroll
            for (int nt = 0; nt < 4; ++nt) {
                f16x8 bfv = *(const f16x8*)
                    &w_s[((kt * 4 + q) * 128 + n0w + nt * 16 + r) * 8];
                acc[nt] = __builtin_amdgcn_mfma_f32_16x16x32_f16(
                    af, bfv, acc[nt], 0, 0, 0);
            }
        }
        __syncthreads();
    }
    if (region == 0) {
#pragma unroll
        for (int nt = 0; nt < 4; ++nt) {
            int n = n0b + n0w + nt * 16 + r;
#pragma unroll
            for (int rr = 0; rr < 4; ++rr)
                imgHf[(size_t)(r0 + m0 + 4 * q + rr) * HH + n] =
                    (_Float16)acc[nt][rr];
        }
    } else if (region == 1) {
#pragma unroll
        for (int nt = 0; nt < 4; ++nt) {
            int n = n0b + n0w + nt * 16 + r;
            float bv = b1[n];
#pragma unroll
            for (int rr = 0; rr < 4; ++rr)
                labHf[(size_t)(r0 + m0 + 4 * q + rr) * HH + n] =
                    (_Float16)(acc[nt][rr] + bv);
        }
    } else {
#pragma unroll
        for (int nt = 0; nt < 4; ++nt) {
            int k = n0w + nt * 16 + r;
            float bv = conv_b[k];
#pragma unroll
            for (int rr = 0; rr < 4; ++rr) {
                int row = r0 + m0 + 4 * q + rr;
                int b = row >> 9, t = row & 511;
                seg_out[((size_t)b * KK + k) * TT + t] =
                    (acc[nt][rr] + bv) * masks[row];
            }
        }
    }
}

// ---------------- joint: zero-LDS h (tanh -> A-frags in regs), dbuf LDS W2,
// one barrier/chunk, fp16 everywhere, exp-based tanh, in-register log-softmax.
__global__ __launch_bounds__(256) void joint_kernel6(
    const _Float16* __restrict__ imgHf,  // [B*T][H]
    const _Float16* __restrict__ labHf,  // [B*U][H] (b1 folded)
    const _Float16* __restrict__ W2s,    // swizzled [(h>>3)][k][h&7]
    const float* __restrict__ b2,
    float* __restrict__ out) {           // [B*U*T][K]
    __shared__ __align__(16) _Float16 w_s[2][8192];  // 2 x 16 KB
    int tid = threadIdx.x, bid = blockIdx.x;
    int t0 = (bid & 7) * 64;
    int rest = bid >> 3;
    int u = rest % UU, b = rest / UU;
    int lane = tid & 63, wv = tid >> 6;
    int q = lane >> 4, r = lane & 15;
    // this lane's h row and A-fragment columns
    const _Float16* imgrow = imgHf + ((size_t)b * TT + t0 + wv * 16 + r) * HH;
    const _Float16* labrow = labHf + (size_t)(b * UU + u) * HH;
    int c0 = q * 8, c1 = 32 + q * 8;
    int ws_off = tid * 8;
    floatx4 acc[8] = {};
    // prologue: chunk 0 W2 -> LDS buf0; img/lab chunk 0 -> regs
    f16x8 ivA = *(const f16x8*)&imgrow[c0];
    f16x8 ivB = *(const f16x8*)&imgrow[c1];
    f16x8 lvA = *(const f16x8*)&labrow[c0];
    f16x8 lvB = *(const f16x8*)&labrow[c1];
    {
        const _Float16* wsrc = W2s;
#pragma unroll
        for (int i2 = 0; i2 < 4; ++i2)
            *(f16x8*)&w_s[0][i2 * 2048 + ws_off] =
                *(const f16x8*)&wsrc[i2 * 2048 + ws_off];
    }
    __syncthreads();
#pragma unroll 2
    for (int c = 0; c < 16; ++c) {
        int buf = c & 1;
        // issue next chunk's loads first; they drain during tanh+MFMA
        f16x8 nivA, nivB, nlvA, nlvB, nw0, nw1, nw2, nw3;
        if (c < 15) {
            int cb = (c + 1) * 64;
            nivA = *(const f16x8*)&imgrow[cb + c0];
            nivB = *(const f16x8*)&imgrow[cb + c1];
            nlvA = *(const f16x8*)&labrow[cb + c0];
            nlvB = *(const f16x8*)&labrow[cb + c1];
            const _Float16* wsrc = W2s + (size_t)(c + 1) * 8192;
            nw0 = *(const f16x8*)&wsrc[0 * 2048 + ws_off];
            nw1 = *(const f16x8*)&wsrc[1 * 2048 + ws_off];
            nw2 = *(const f16x8*)&wsrc[2 * 2048 + ws_off];
            nw3 = *(const f16x8*)&wsrc[3 * 2048 + ws_off];
        }
        // h = tanh(img + lab): packed f16 add, exp-tanh, straight into A-frags
        f16x8 a0 = tanh8(ivA + lvA);
        f16x8 a1 = tanh8(ivB + lvB);
#pragma unroll
        for (int nt = 0; nt < 8; ++nt) {
            f16x8 bf0 = *(const f16x8*)&w_s[buf][((0 + q) * 128 + nt * 16 + r) * 8];
            acc[nt] = __builtin_amdgcn_mfma_f32_16x16x32_f16(
                a0, bf0, acc[nt], 0, 0, 0);
        }
#pragma unroll
        for (int nt = 0; nt < 8; ++nt) {
            f16x8 bf1 = *(const f16x8*)&w_s[buf][((4 + q) * 128 + nt * 16 + r) * 8];
            acc[nt] = __builtin_amdgcn_mfma_f32_16x16x32_f16(
                a1, bf1, acc[nt], 0, 0, 0);
        }
        if (c < 15) {  // stage next W2 chunk into other buffer; rotate regs
            *(f16x8*)&w_s[buf ^ 1][0 * 2048 + ws_off] = nw0;
            *(f16x8*)&w_s[buf ^ 1][1 * 2048 + ws_off] = nw1;
            *(f16x8*)&w_s[buf ^ 1][2 * 2048 + ws_off] = nw2;
            *(f16x8*)&w_s[buf ^ 1][3 * 2048 + ws_off] = nw3;
            ivA = nivA; ivB = nivB; lvA = nlvA; lvB = nlvB;
        }
        __syncthreads();
    }
    // epilogue: +b2, in-register log-softmax over this 16-lane group's 128 cols
    float b2v[8];
#pragma unroll
    for (int nt = 0; nt < 8; ++nt) b2v[nt] = b2[nt * 16 + r];
    float* orow = out + (((size_t)b * UU + u) * TT + t0 + wv * 16) * KK;
#pragma unroll
    for (int rr = 0; rr < 4; ++rr) {
        float v[8];
        float mx = -INFINITY;
#pragma unroll
        for (int nt = 0; nt < 8; ++nt) {
            v[nt] = acc[nt][rr] + b2v[nt];
            mx = fmaxf(mx, v[nt]);
        }
        mx = fmaxf(mx, __shfl_xor(mx, 1, 16));
        mx = fmaxf(mx, __shfl_xor(mx, 2, 16));
        mx = fmaxf(mx, __shfl_xor(mx, 4, 16));
        mx = fmaxf(mx, __shfl_xor(mx, 8, 16));
        float s = 0.f;
#pragma unroll
        for (int nt = 0; nt < 8; ++nt) s += __expf(v[nt] - mx);
        s += __shfl_xor(s, 1, 16);
        s += __shfl_xor(s, 2, 16);
        s += __shfl_xor(s, 4, 16);
        s += __shfl_xor(s, 8, 16);
        float lse = mx + __logf(s);
        int row = 4 * q + rr;
#pragma unroll
        for (int nt = 0; nt < 8; ++nt)
            orow[(size_t)row * KK + nt * 16 + r] = v[nt] - lse;
    }
}

extern "C" void kernel_launch(void* const* d_in, const int* in_sizes, int n_in,
                              void* d_out, int out_size, void* d_ws, size_t ws_size,
                              hipStream_t stream) {
    const float* img    = (const float*)d_in[0];
    const float* labf   = (const float*)d_in[1];
    const float* masks  = (const float*)d_in[2];
    const float* W1     = (const float*)d_in[3];
    const float* b1     = (const float*)d_in[4];
    const float* W2     = (const float*)d_in[5];
    const float* b2     = (const float*)d_in[6];
    const float* conv_w = (const float*)d_in[7];
    const float* conv_b = (const float*)d_in[8];
    float* out = (float*)d_out;

    _Float16* base  = (_Float16*)d_ws;
    _Float16* imgHf = base;                    // [1024][1024]
    _Float16* labHf = imgHf + 1024 * 1024;     // [96][1024]
    _Float16* W2s   = labHf + 96 * 1024;       // [H/8][K][8] = 131072

    mid_kernel4<<<328, 256, 0, stream>>>(img, labf, W1, W2, conv_w,
                                         b1, conv_b, masks,
                                         imgHf, labHf, W2s, out);
    joint_kernel6<<<768, 256, 0, stream>>>(imgHf, labHf, W2s, b2,
                                           out + (size_t)BB * KK * TT);
}